// Round 1
// baseline (253.182 us; speedup 1.0000x reference)
//
#include <hip/hip_runtime.h>

// Problem constants (from reference)
#define NNODES 100000
#define NEDGES 3200000
#define DIM    128

typedef __bf16  bf16x8 __attribute__((ext_vector_type(8)));
typedef unsigned short u16;
typedef u16     u16x8  __attribute__((ext_vector_type(8)));
typedef float   f32x4  __attribute__((ext_vector_type(4)));
typedef unsigned int u32;
typedef u32     u32x4  __attribute__((ext_vector_type(4)));

__device__ __forceinline__ u16 f2bf(float f) {
    // round-to-nearest-even f32 -> bf16
    union { float f; unsigned int i; } c;
    c.f = f;
    unsigned int x = c.i;
    unsigned int rounding = 0x7fff + ((x >> 16) & 1);
    x += rounding;
    return (u16)(x >> 16);
}

__device__ __forceinline__ float asf(u32 u) {
    union { u32 i; float f; } c; c.i = u; return c.f;
}

__device__ __forceinline__ bf16x8 ldfrag_u16(const u16* p) {
    u16x8 u = *(const u16x8*)p;
    return __builtin_bit_cast(bf16x8, u);
}

// load 8 consecutive fp32, convert to bf16x8 fragment (RNE)
__device__ __forceinline__ bf16x8 ldfrag_f32(const float* p) {
    f32x4 a = *(const f32x4*)p;
    f32x4 b = *(const f32x4*)(p + 4);
    u16x8 u;
#pragma unroll
    for (int i = 0; i < 4; ++i) u[i] = f2bf(a[i]);
#pragma unroll
    for (int i = 0; i < 4; ++i) u[4 + i] = f2bf(b[i]);
    return __builtin_bit_cast(bf16x8, u);
}

// ---------------------------------------------------------------------------
// Kernel 1: CSR row_ptr from sorted edge_row via binary search.
__global__ void build_row_ptr(const int* __restrict__ edge_row,
                              int* __restrict__ row_ptr) {
    int n = blockIdx.x * blockDim.x + threadIdx.x;
    if (n > NNODES) return;
    int lo = 0, hi = NEDGES;
    while (lo < hi) {
        int mid = (lo + hi) >> 1;
        if (edge_row[mid] < n) lo = mid + 1; else hi = mid;
    }
    row_ptr[n] = lo;
}

// ---------------------------------------------------------------------------
// Kernel 2: Wt[n][k] = bf16(W[k][n])  (fp32 -> bf16 transpose, 128x128)
__global__ void prep_wt(const float* __restrict__ w, u16* __restrict__ wt) {
    int i = blockIdx.x * blockDim.x + threadIdx.x;
    if (i >= DIM * DIM) return;
    int k = i >> 7, n = i & 127;
    wt[n * DIM + k] = f2bf(w[k * DIM + n]);
}

// ---------------------------------------------------------------------------
// Kernel 3: y = bf16(x) @ bf16(W)  (fp32 in, bf16 out, fp32 MFMA accumulate)
// Wt staged in LDS (padded stride 136 u16). 4 waves/block, 16 rows/wave.
// y written through a per-wave LDS bounce tile -> 4x coalesced 1KB stores.
#define WT_STRIDE 136   // u16 units; 272B rows, 16B aligned, breaks pow2 banks
__global__ __launch_bounds__(256) void gemm_xw(const float* __restrict__ x,
                                               const u16* __restrict__ wt,
                                               u16* __restrict__ y) {
    __shared__ u16 wlds[DIM * WT_STRIDE];     // 34816 B
    __shared__ u16 ybounce[4][16 * DIM];      // 4 waves x 4KB = 16384 B

    int tid = threadIdx.x;
    // cooperative staged copy of Wt (128 rows x 256B) into padded LDS
    {
        const f32x4* src = (const f32x4*)wt;   // 16B chunks, 16 per row
#pragma unroll
        for (int i = 0; i < 8; ++i) {
            int ci  = tid + 256 * i;           // 0..2047
            int row = ci >> 4, off = ci & 15;
            *((f32x4*)(wlds + row * WT_STRIDE) + off) = src[ci];
        }
    }
    __syncthreads();

    int wave = __builtin_amdgcn_readfirstlane(tid >> 6);
    int lane = tid & 63;
    int quad = lane >> 4, l16 = lane & 15;
    int mBase = (blockIdx.x * 4 + wave) * 16;
    if (mBase >= NNODES) return;

    const float* xrow = x + (size_t)(mBase + l16) * DIM + quad * 8;

    f32x4 acc[8];
#pragma unroll
    for (int nt = 0; nt < 8; ++nt) acc[nt] = (f32x4){0.f, 0.f, 0.f, 0.f};

#pragma unroll
    for (int kb = 0; kb < 4; ++kb) {
        bf16x8 a = ldfrag_f32(xrow + kb * 32);
#pragma unroll
        for (int nt = 0; nt < 8; ++nt) {
            bf16x8 b = ldfrag_u16(wlds + (nt * 16 + l16) * WT_STRIDE + kb * 32 + quad * 8);
            acc[nt] = __builtin_amdgcn_mfma_f32_16x16x32_bf16(a, b, acc[nt], 0, 0, 0);
        }
    }

    // bounce C-layout -> row-major in per-wave LDS region, then coalesced store
    u16* yb = ybounce[wave];
#pragma unroll
    for (int nt = 0; nt < 8; ++nt) {
        int col = nt * 16 + l16;
#pragma unroll
        for (int r = 0; r < 4; ++r)
            yb[(quad * 4 + r) * DIM + col] = f2bf(acc[nt][r]);
    }
#pragma unroll
    for (int j = 0; j < 4; ++j) {
        int lr = j * 4 + quad;                 // 0..15
        u16x8 t = *(const u16x8*)(yb + lr * DIM + l16 * 8);
        *(u16x8*)(y + (size_t)(mBase + lr) * DIM + l16 * 8) = t;
    }
}

// ---------------------------------------------------------------------------
// Kernel 4: out[n][p*64:(p+1)*64] = bias_half + sum_{e in row n} val[e] * y[col[e]][half p]
//
// TWO-PHASE COLUMN SPLIT: grid = 2 x 25000 blocks. Blocks [0,25000) gather only
// the first 64 columns of y (12.8 MB live footprint), blocks [25000,50000) the
// second 64. Block dispatch is ~in-order, so the phases are temporally
// separated and the per-XCD L2 (4 MB) sees HALF the gather working set ->
// higher hit rate -> less fabric/L3 traffic (the measured bottleneck:
// FETCH_SIZE 365 MB vs ~52 MB compulsory). Cost: ecol/eval streamed twice
// (+25.6 MB sequential, cheap vs ~120 MB of random-miss savings).
//
// One wave per (row, phase). Half-row = 128 B = one cache line, fully used.
// OCT-EDGE GATHER: one global_load_dwordx4 fetches 16B chunks of EIGHT
// different y half-rows (lane l: edge grp=l>>3, chunk sub=l&7) = 1KB/inst.
// __shfl_xor(8|16|32) tree merges the 8 edge groups at the end.
__global__ __launch_bounds__(256, 8) void spmm(const int* __restrict__ row_ptr,
                                               const int* __restrict__ ecol,
                                               const float* __restrict__ eval,
                                               const u16* __restrict__ y,
                                               const float* __restrict__ bias,
                                               float* __restrict__ out) {
    int lane  = threadIdx.x & 63;
    int wave  = threadIdx.x >> 6;
    int bid   = blockIdx.x;
    int phase = (bid >= (NNODES / 4)) ? 1 : 0;              // uniform
    int rb    = bid - phase * (NNODES / 4);
    int row   = __builtin_amdgcn_readfirstlane(rb * 4 + wave);

    int lo = row_ptr[row];
    int hi = row_ptr[row + 1];

    int grp = lane >> 3;   // which edge of the oct this lane serves (0..7)
    int sub = lane & 7;    // which 16B chunk of the 128B half-row (0..7)

    float acc[8];
#pragma unroll
    for (int j = 0; j < 8; ++j) acc[j] = 0.f;

    const u16* ychunk = y + (size_t)phase * 64 + sub * 8;

    int e = lo;
    // main loop: 16 edges per iteration, 2 gather insts of 1KB each
    for (; e + 16 <= hi; e += 16) {
        int   ca = ecol[e + grp];
        int   cb = ecol[e + 8 + grp];
        float va = eval[e + grp];
        float vb = eval[e + 8 + grp];
        u32x4 qa = *(const u32x4*)(ychunk + (size_t)ca * DIM);
        u32x4 qb = *(const u32x4*)(ychunk + (size_t)cb * DIM);
#pragma unroll
        for (int j = 0; j < 4; ++j) {
            acc[2 * j]     += va * asf(qa[j] << 16);
            acc[2 * j + 1] += va * asf(qa[j] & 0xffff0000u);
        }
#pragma unroll
        for (int j = 0; j < 4; ++j) {
            acc[2 * j]     += vb * asf(qb[j] << 16);
            acc[2 * j + 1] += vb * asf(qb[j] & 0xffff0000u);
        }
    }
    // tail: 8 edges per pass, padded lanes use last edge with v=0
    for (; e < hi; e += 8) {
        int idx  = e + grp;
        int live = idx < hi;
        int   c  = ecol[live ? idx : hi - 1];
        float v  = live ? eval[idx] : 0.f;
        u32x4 q  = *(const u32x4*)(ychunk + (size_t)c * DIM);
#pragma unroll
        for (int j = 0; j < 4; ++j) {
            acc[2 * j]     += v * asf(q[j] << 16);
            acc[2 * j + 1] += v * asf(q[j] & 0xffff0000u);
        }
    }

    // merge the 8 lane-groups (same sub, grp 0..7)
#pragma unroll
    for (int j = 0; j < 8; ++j) {
        acc[j] += __shfl_xor(acc[j], 8);
        acc[j] += __shfl_xor(acc[j], 16);
        acc[j] += __shfl_xor(acc[j], 32);
    }

    if (grp == 0) {
        int   cb   = phase * 64 + sub * 8;
        float* orow = out + (size_t)row * DIM + cb;
        f32x4 o0, o1;
#pragma unroll
        for (int j = 0; j < 4; ++j) {
            o0[j] = acc[j]     + bias[cb + j];
            o1[j] = acc[4 + j] + bias[cb + 4 + j];
        }
        __builtin_nontemporal_store(o0, (f32x4*)orow);
        __builtin_nontemporal_store(o1, (f32x4*)(orow + 4));
    }
}

// ---------------------------------------------------------------------------
extern "C" void kernel_launch(void* const* d_in, const int* in_sizes, int n_in,
                              void* d_out, int out_size, void* d_ws, size_t ws_size,
                              hipStream_t stream) {
    const float* x        = (const float*)d_in[0];  // [NNODES, DIM] fp32
    const int*   edge_row = (const int*)d_in[1];    // [NEDGES] int32 (sorted)
    const int*   edge_col = (const int*)d_in[2];    // [NEDGES] int32
    const float* edge_val = (const float*)d_in[3];  // [NEDGES] fp32
    const float* weight   = (const float*)d_in[4];  // [DIM, DIM] fp32
    const float* bias     = (const float*)d_in[5];  // [DIM] fp32
    float* out = (float*)d_out;                     // [NNODES, DIM] fp32

    char* ws = (char*)d_ws;
    // layout: y bf16 [NNODES*DIM] | row_ptr int[NNODES+1] | Wt bf16 [DIM*DIM]
    u16* y       = (u16*)ws;                               // 25,600,000 B
    int* row_ptr = (int*)(ws + (size_t)NNODES * DIM * 2);  // 400,004 B
    u16* wt      = (u16*)(ws + 26000128);                  // 32,768 B (16B aligned)

    prep_wt<<<(DIM * DIM + 255) / 256, 256, 0, stream>>>(weight, wt);
    build_row_ptr<<<(NNODES + 1 + 255) / 256, 256, 0, stream>>>(edge_row, row_ptr);

    // y = x @ W : 6250 wave-rows of 16, 4 waves/block -> 1563 blocks
    gemm_xw<<<(NNODES / 16 + 3) / 4, 256, 0, stream>>>(x, wt, y);

    // out = A @ y + bias : one wave per (row, colhalf), 2-phase column split
    spmm<<<2 * (NNODES / 4), 256, 0, stream>>>(row_ptr, edge_col, edge_val, y, bias, out);
}

// Round 2
// 246.353 us; speedup vs baseline: 1.0277x; 1.0277x over previous
//
#include <hip/hip_runtime.h>

// Problem constants (from reference)
#define NNODES 100000
#define NEDGES 3200000
#define DIM    128

typedef __bf16  bf16x8 __attribute__((ext_vector_type(8)));
typedef unsigned short u16;
typedef u16     u16x8  __attribute__((ext_vector_type(8)));
typedef float   f32x4  __attribute__((ext_vector_type(4)));
typedef unsigned int u32;
typedef u32     u32x4  __attribute__((ext_vector_type(4)));

__device__ __forceinline__ u16 f2bf(float f) {
    // round-to-nearest-even f32 -> bf16
    union { float f; unsigned int i; } c;
    c.f = f;
    unsigned int x = c.i;
    unsigned int rounding = 0x7fff + ((x >> 16) & 1);
    x += rounding;
    return (u16)(x >> 16);
}

__device__ __forceinline__ float asf(u32 u) {
    union { u32 i; float f; } c; c.i = u; return c.f;
}

__device__ __forceinline__ bf16x8 ldfrag_u16(const u16* p) {
    u16x8 u = *(const u16x8*)p;
    return __builtin_bit_cast(bf16x8, u);
}

// load 8 consecutive fp32, convert to bf16x8 fragment (RNE)
__device__ __forceinline__ bf16x8 ldfrag_f32(const float* p) {
    f32x4 a = *(const f32x4*)p;
    f32x4 b = *(const f32x4*)(p + 4);
    u16x8 u;
#pragma unroll
    for (int i = 0; i < 4; ++i) u[i] = f2bf(a[i]);
#pragma unroll
    for (int i = 0; i < 4; ++i) u[4 + i] = f2bf(b[i]);
    return __builtin_bit_cast(bf16x8, u);
}

// ---------------------------------------------------------------------------
// Kernel 1: CSR row_ptr from sorted edge_row via binary search.
__global__ void build_row_ptr(const int* __restrict__ edge_row,
                              int* __restrict__ row_ptr) {
    int n = blockIdx.x * blockDim.x + threadIdx.x;
    if (n > NNODES) return;
    int lo = 0, hi = NEDGES;
    while (lo < hi) {
        int mid = (lo + hi) >> 1;
        if (edge_row[mid] < n) lo = mid + 1; else hi = mid;
    }
    row_ptr[n] = lo;
}

// ---------------------------------------------------------------------------
// Kernel 2: Wt[n][k] = bf16(W[k][n])  (fp32 -> bf16 transpose, 128x128)
__global__ void prep_wt(const float* __restrict__ w, u16* __restrict__ wt) {
    int i = blockIdx.x * blockDim.x + threadIdx.x;
    if (i >= DIM * DIM) return;
    int k = i >> 7, n = i & 127;
    wt[n * DIM + k] = f2bf(w[k * DIM + n]);
}

// ---------------------------------------------------------------------------
// Kernel 3: y = bf16(x) @ bf16(W)  (fp32 in, bf16 out, fp32 MFMA accumulate)
// Wt staged in LDS (padded stride 136 u16). 4 waves/block, 16 rows/wave.
// y written through a per-wave LDS bounce tile -> 4x coalesced 1KB stores.
#define WT_STRIDE 136   // u16 units; 272B rows, 16B aligned, breaks pow2 banks
__global__ __launch_bounds__(256) void gemm_xw(const float* __restrict__ x,
                                               const u16* __restrict__ wt,
                                               u16* __restrict__ y) {
    __shared__ u16 wlds[DIM * WT_STRIDE];     // 34816 B
    __shared__ u16 ybounce[4][16 * DIM];      // 4 waves x 4KB = 16384 B

    int tid = threadIdx.x;
    // cooperative staged copy of Wt (128 rows x 256B) into padded LDS
    {
        const f32x4* src = (const f32x4*)wt;   // 16B chunks, 16 per row
#pragma unroll
        for (int i = 0; i < 8; ++i) {
            int ci  = tid + 256 * i;           // 0..2047
            int row = ci >> 4, off = ci & 15;
            *((f32x4*)(wlds + row * WT_STRIDE) + off) = src[ci];
        }
    }
    __syncthreads();

    int wave = __builtin_amdgcn_readfirstlane(tid >> 6);
    int lane = tid & 63;
    int quad = lane >> 4, l16 = lane & 15;
    int mBase = (blockIdx.x * 4 + wave) * 16;
    if (mBase >= NNODES) return;

    const float* xrow = x + (size_t)(mBase + l16) * DIM + quad * 8;

    f32x4 acc[8];
#pragma unroll
    for (int nt = 0; nt < 8; ++nt) acc[nt] = (f32x4){0.f, 0.f, 0.f, 0.f};

#pragma unroll
    for (int kb = 0; kb < 4; ++kb) {
        bf16x8 a = ldfrag_f32(xrow + kb * 32);
#pragma unroll
        for (int nt = 0; nt < 8; ++nt) {
            bf16x8 b = ldfrag_u16(wlds + (nt * 16 + l16) * WT_STRIDE + kb * 32 + quad * 8);
            acc[nt] = __builtin_amdgcn_mfma_f32_16x16x32_bf16(a, b, acc[nt], 0, 0, 0);
        }
    }

    // bounce C-layout -> row-major in per-wave LDS region, then coalesced store
    u16* yb = ybounce[wave];
#pragma unroll
    for (int nt = 0; nt < 8; ++nt) {
        int col = nt * 16 + l16;
#pragma unroll
        for (int r = 0; r < 4; ++r)
            yb[(quad * 4 + r) * DIM + col] = f2bf(acc[nt][r]);
    }
#pragma unroll
    for (int j = 0; j < 4; ++j) {
        int lr = j * 4 + quad;                 // 0..15
        u16x8 t = *(const u16x8*)(yb + lr * DIM + l16 * 8);
        *(u16x8*)(y + (size_t)(mBase + lr) * DIM + l16 * 8) = t;
    }
}

// ---------------------------------------------------------------------------
// Kernel 4: out[n][p*64:(p+1)*64] = bias_half + sum_{e in row n} val[e] * y[col[e]][half p]
//
// TWO-PHASE COLUMN SPLIT (kept from R1: -41MB FETCH): blocks [0,25000) gather
// only cols 0..63 of y (12.8 MB live footprint), blocks [25000,50000) cols
// 64..127. R1 post-mortem: the split alone REGRESSED time (118 vs 109 us)
// because per-wave MLP halved (2 outstanding gathers/iter vs 4) and the
// 1-gather-per-pass tail is latency-serial. Fix here:
//   * 32-edge main iteration -> FOUR 1KB oct-gathers issued back-to-back
//   * tail folded into the main loop via clamp-masking (dead slots read
//     ecol[hi-1]'s line = L1 broadcast hit, v=0) -> no serial tail at all.
// A mean-degree-32 row = exactly one 4-deep-MLP iteration.
//
// One wave per (row, phase). Half-row = 128 B = one cache line, fully used.
// Lane l: edge grp=l>>3 (0..7), chunk sub=l&7. __shfl_xor(8|16|32) merges.
__global__ __launch_bounds__(256, 8) void spmm(const int* __restrict__ row_ptr,
                                               const int* __restrict__ ecol,
                                               const float* __restrict__ eval,
                                               const u16* __restrict__ y,
                                               const float* __restrict__ bias,
                                               float* __restrict__ out) {
    int lane  = threadIdx.x & 63;
    int wave  = threadIdx.x >> 6;
    int bid   = blockIdx.x;
    int phase = (bid >= (NNODES / 4)) ? 1 : 0;              // uniform
    int rb    = bid - phase * (NNODES / 4);
    int row   = __builtin_amdgcn_readfirstlane(rb * 4 + wave);

    int lo = row_ptr[row];
    int hi = row_ptr[row + 1];

    int grp = lane >> 3;   // which edge of the oct this lane serves (0..7)
    int sub = lane & 7;    // which 16B chunk of the 128B half-row (0..7)

    float acc[8];
#pragma unroll
    for (int j = 0; j < 8; ++j) acc[j] = 0.f;

    const u16* ychunk = y + (size_t)phase * 64 + sub * 8;

    // 32 edges per iteration, 4 clamp-masked 1KB gathers in flight; no tail.
    for (int e = lo; e < hi; e += 32) {
        int   cc[4];
        float vv[4];
#pragma unroll
        for (int k = 0; k < 4; ++k) {
            int idx  = e + k * 8 + grp;
            int live = idx < hi;
            cc[k] = ecol[live ? idx : hi - 1];
            vv[k] = live ? eval[idx] : 0.f;
        }
        u32x4 q[4];
#pragma unroll
        for (int k = 0; k < 4; ++k)
            q[k] = *(const u32x4*)(ychunk + (size_t)cc[k] * DIM);
#pragma unroll
        for (int k = 0; k < 4; ++k) {
#pragma unroll
            for (int j = 0; j < 4; ++j) {
                acc[2 * j]     += vv[k] * asf(q[k][j] << 16);
                acc[2 * j + 1] += vv[k] * asf(q[k][j] & 0xffff0000u);
            }
        }
    }

    // merge the 8 lane-groups (same sub, grp 0..7)
#pragma unroll
    for (int j = 0; j < 8; ++j) {
        acc[j] += __shfl_xor(acc[j], 8);
        acc[j] += __shfl_xor(acc[j], 16);
        acc[j] += __shfl_xor(acc[j], 32);
    }

    if (grp == 0) {
        int   cb   = phase * 64 + sub * 8;
        float* orow = out + (size_t)row * DIM + cb;
        f32x4 o0, o1;
#pragma unroll
        for (int j = 0; j < 4; ++j) {
            o0[j] = acc[j]     + bias[cb + j];
            o1[j] = acc[4 + j] + bias[cb + 4 + j];
        }
        __builtin_nontemporal_store(o0, (f32x4*)orow);
        __builtin_nontemporal_store(o1, (f32x4*)(orow + 4));
    }
}

// ---------------------------------------------------------------------------
extern "C" void kernel_launch(void* const* d_in, const int* in_sizes, int n_in,
                              void* d_out, int out_size, void* d_ws, size_t ws_size,
                              hipStream_t stream) {
    const float* x        = (const float*)d_in[0];  // [NNODES, DIM] fp32
    const int*   edge_row = (const int*)d_in[1];    // [NEDGES] int32 (sorted)
    const int*   edge_col = (const int*)d_in[2];    // [NEDGES] int32
    const float* edge_val = (const float*)d_in[3];  // [NEDGES] fp32
    const float* weight   = (const float*)d_in[4];  // [DIM, DIM] fp32
    const float* bias     = (const float*)d_in[5];  // [DIM] fp32
    float* out = (float*)d_out;                     // [NNODES, DIM] fp32

    char* ws = (char*)d_ws;
    // layout: y bf16 [NNODES*DIM] | row_ptr int[NNODES+1] | Wt bf16 [DIM*DIM]
    u16* y       = (u16*)ws;                               // 25,600,000 B
    int* row_ptr = (int*)(ws + (size_t)NNODES * DIM * 2);  // 400,004 B
    u16* wt      = (u16*)(ws + 26000128);                  // 32,768 B (16B aligned)

    prep_wt<<<(DIM * DIM + 255) / 256, 256, 0, stream>>>(weight, wt);
    build_row_ptr<<<(NNODES + 1 + 255) / 256, 256, 0, stream>>>(edge_row, row_ptr);

    // y = x @ W : 6250 wave-rows of 16, 4 waves/block -> 1563 blocks
    gemm_xw<<<(NNODES / 16 + 3) / 4, 256, 0, stream>>>(x, wt, y);

    // out = A @ y + bias : one wave per (row, colhalf), 2-phase column split
    spmm<<<2 * (NNODES / 4), 256, 0, stream>>>(row_ptr, edge_col, edge_val, y, bias, out);
}

// Round 3
// 243.799 us; speedup vs baseline: 1.0385x; 1.0105x over previous
//
#include <hip/hip_runtime.h>

// Problem constants (from reference)
#define NNODES 100000
#define NEDGES 3200000
#define DIM    128

typedef __bf16  bf16x8 __attribute__((ext_vector_type(8)));
typedef unsigned short u16;
typedef u16     u16x8  __attribute__((ext_vector_type(8)));
typedef float   f32x4  __attribute__((ext_vector_type(4)));
typedef unsigned int u32;
typedef u32     u32x4  __attribute__((ext_vector_type(4)));

__device__ __forceinline__ u16 f2bf(float f) {
    // round-to-nearest-even f32 -> bf16
    union { float f; unsigned int i; } c;
    c.f = f;
    unsigned int x = c.i;
    unsigned int rounding = 0x7fff + ((x >> 16) & 1);
    x += rounding;
    return (u16)(x >> 16);
}

__device__ __forceinline__ float asf(u32 u) {
    union { u32 i; float f; } c; c.i = u; return c.f;
}

__device__ __forceinline__ bf16x8 ldfrag_u16(const u16* p) {
    u16x8 u = *(const u16x8*)p;
    return __builtin_bit_cast(bf16x8, u);
}

// load 8 consecutive fp32, convert to bf16x8 fragment (RNE)
__device__ __forceinline__ bf16x8 ldfrag_f32(const float* p) {
    f32x4 a = *(const f32x4*)p;
    f32x4 b = *(const f32x4*)(p + 4);
    u16x8 u;
#pragma unroll
    for (int i = 0; i < 4; ++i) u[i] = f2bf(a[i]);
#pragma unroll
    for (int i = 0; i < 4; ++i) u[4 + i] = f2bf(b[i]);
    return __builtin_bit_cast(bf16x8, u);
}

// ---------------------------------------------------------------------------
// Kernel 1: CSR row_ptr from sorted edge_row via binary search.
__global__ void build_row_ptr(const int* __restrict__ edge_row,
                              int* __restrict__ row_ptr) {
    int n = blockIdx.x * blockDim.x + threadIdx.x;
    if (n > NNODES) return;
    int lo = 0, hi = NEDGES;
    while (lo < hi) {
        int mid = (lo + hi) >> 1;
        if (edge_row[mid] < n) lo = mid + 1; else hi = mid;
    }
    row_ptr[n] = lo;
}

// ---------------------------------------------------------------------------
// Kernel 2: Wt[n][k] = bf16(W[k][n])  (fp32 -> bf16 transpose, 128x128)
__global__ void prep_wt(const float* __restrict__ w, u16* __restrict__ wt) {
    int i = blockIdx.x * blockDim.x + threadIdx.x;
    if (i >= DIM * DIM) return;
    int k = i >> 7, n = i & 127;
    wt[n * DIM + k] = f2bf(w[k * DIM + n]);
}

// ---------------------------------------------------------------------------
// Kernel 3: y = bf16(x) @ bf16(W)  (fp32 in, bf16 out, fp32 MFMA accumulate)
// Wt staged in LDS (padded stride 136 u16). 4 waves/block, 16 rows/wave.
// y written through a per-wave LDS bounce tile -> 4x coalesced 1KB stores.
#define WT_STRIDE 136   // u16 units; 272B rows, 16B aligned, breaks pow2 banks
__global__ __launch_bounds__(256) void gemm_xw(const float* __restrict__ x,
                                               const u16* __restrict__ wt,
                                               u16* __restrict__ y) {
    __shared__ u16 wlds[DIM * WT_STRIDE];     // 34816 B
    __shared__ u16 ybounce[4][16 * DIM];      // 4 waves x 4KB = 16384 B

    int tid = threadIdx.x;
    // cooperative staged copy of Wt (128 rows x 256B) into padded LDS
    {
        const f32x4* src = (const f32x4*)wt;   // 16B chunks, 16 per row
#pragma unroll
        for (int i = 0; i < 8; ++i) {
            int ci  = tid + 256 * i;           // 0..2047
            int row = ci >> 4, off = ci & 15;
            *((f32x4*)(wlds + row * WT_STRIDE) + off) = src[ci];
        }
    }
    __syncthreads();

    int wave = __builtin_amdgcn_readfirstlane(tid >> 6);
    int lane = tid & 63;
    int quad = lane >> 4, l16 = lane & 15;
    int mBase = (blockIdx.x * 4 + wave) * 16;
    if (mBase >= NNODES) return;

    const float* xrow = x + (size_t)(mBase + l16) * DIM + quad * 8;

    f32x4 acc[8];
#pragma unroll
    for (int nt = 0; nt < 8; ++nt) acc[nt] = (f32x4){0.f, 0.f, 0.f, 0.f};

#pragma unroll
    for (int kb = 0; kb < 4; ++kb) {
        bf16x8 a = ldfrag_f32(xrow + kb * 32);
#pragma unroll
        for (int nt = 0; nt < 8; ++nt) {
            bf16x8 b = ldfrag_u16(wlds + (nt * 16 + l16) * WT_STRIDE + kb * 32 + quad * 8);
            acc[nt] = __builtin_amdgcn_mfma_f32_16x16x32_bf16(a, b, acc[nt], 0, 0, 0);
        }
    }

    // bounce C-layout -> row-major in per-wave LDS region, then coalesced store
    u16* yb = ybounce[wave];
#pragma unroll
    for (int nt = 0; nt < 8; ++nt) {
        int col = nt * 16 + l16;
#pragma unroll
        for (int r = 0; r < 4; ++r)
            yb[(quad * 4 + r) * DIM + col] = f2bf(acc[nt][r]);
    }
#pragma unroll
    for (int j = 0; j < 4; ++j) {
        int lr = j * 4 + quad;                 // 0..15
        u16x8 t = *(const u16x8*)(yb + lr * DIM + l16 * 8);
        *(u16x8*)(y + (size_t)(mBase + lr) * DIM + l16 * 8) = t;
    }
}

// ---------------------------------------------------------------------------
// Kernel 4: out[n][p*64:(p+1)*64] = bias_half + sum_{e in row n} val[e] * y[col[e]][half p]
//
// TWO-PHASE COLUMN SPLIT (R1, kept: -41MB FETCH): blocks [0,25000) gather cols
// 0..63 of y (12.8 MB live footprint), blocks [25000,50000) cols 64..127.
// Half-row = 128 B = exactly one cache line, fully consumed.
//
// R2 post-mortem: 32-edge iteration still needed TWO serialized dependence
// rounds for the typical deg~32 row (metadata -> gather -> consume -> repeat),
// capping per-wave MLP at 4 and effective fabric BW at 3.4 TB/s.
//
// R3: 64-EDGE SINGLE-BURST ITERATION. Degree ~ Poisson(32) (sigma 5.7), so
// essentially every row fits in ONE iteration: 16 metadata loads back-to-back,
// then EIGHT clamp-masked 1KB oct-gathers in one burst, then consume. Dead
// slots (k*8 >= deg) collapse to one resident line (R2 counters: clamping
// costs ~0 fetch) and keep vmcnt statically countable (no branches).
// VGPR ~75 -> __launch_bounds__(256,6): 6 waves/SIMD = the 75% occupancy we
// already measure, with ~1.8x the per-wave outstanding gathers.
//
// Lane l: edge grp=l>>3 (0..7), chunk sub=l&7. __shfl_xor(8|16|32) merges.
__global__ __launch_bounds__(256, 6) void spmm(const int* __restrict__ row_ptr,
                                               const int* __restrict__ ecol,
                                               const float* __restrict__ eval,
                                               const u16* __restrict__ y,
                                               const float* __restrict__ bias,
                                               float* __restrict__ out) {
    int lane  = threadIdx.x & 63;
    int wave  = threadIdx.x >> 6;
    int bid   = blockIdx.x;
    int phase = (bid >= (NNODES / 4)) ? 1 : 0;              // uniform
    int rb    = bid - phase * (NNODES / 4);
    int row   = __builtin_amdgcn_readfirstlane(rb * 4 + wave);

    int lo = row_ptr[row];
    int hi = row_ptr[row + 1];

    int grp = lane >> 3;   // which edge of the oct this lane serves (0..7)
    int sub = lane & 7;    // which 16B chunk of the 128B half-row (0..7)

    float acc[8];
#pragma unroll
    for (int j = 0; j < 8; ++j) acc[j] = 0.f;

    const u16* ychunk = y + (size_t)phase * 64 + sub * 8;

    // 64 edges per iteration: 16 metadata loads, then 8 gathers in one burst.
    // For deg ~ Poisson(32) this loop body runs exactly once per row.
    for (int e = lo; e < hi; e += 64) {
        int   cc[8];
        float vv[8];
#pragma unroll
        for (int k = 0; k < 8; ++k) {
            int idx  = e + k * 8 + grp;
            int live = idx < hi;
            int safe = live ? idx : hi - 1;
            cc[k] = ecol[safe];
            vv[k] = live ? eval[safe] : 0.f;
        }
        u32x4 q[8];
#pragma unroll
        for (int k = 0; k < 8; ++k)
            q[k] = *(const u32x4*)(ychunk + (size_t)cc[k] * DIM);
#pragma unroll
        for (int k = 0; k < 8; ++k) {
#pragma unroll
            for (int j = 0; j < 4; ++j) {
                acc[2 * j]     += vv[k] * asf(q[k][j] << 16);
                acc[2 * j + 1] += vv[k] * asf(q[k][j] & 0xffff0000u);
            }
        }
    }

    // merge the 8 lane-groups (same sub, grp 0..7)
#pragma unroll
    for (int j = 0; j < 8; ++j) {
        acc[j] += __shfl_xor(acc[j], 8);
        acc[j] += __shfl_xor(acc[j], 16);
        acc[j] += __shfl_xor(acc[j], 32);
    }

    if (grp == 0) {
        int   cb   = phase * 64 + sub * 8;
        float* orow = out + (size_t)row * DIM + cb;
        f32x4 o0, o1;
#pragma unroll
        for (int j = 0; j < 4; ++j) {
            o0[j] = acc[j]     + bias[cb + j];
            o1[j] = acc[4 + j] + bias[cb + 4 + j];
        }
        __builtin_nontemporal_store(o0, (f32x4*)orow);
        __builtin_nontemporal_store(o1, (f32x4*)(orow + 4));
    }
}

// ---------------------------------------------------------------------------
extern "C" void kernel_launch(void* const* d_in, const int* in_sizes, int n_in,
                              void* d_out, int out_size, void* d_ws, size_t ws_size,
                              hipStream_t stream) {
    const float* x        = (const float*)d_in[0];  // [NNODES, DIM] fp32
    const int*   edge_row = (const int*)d_in[1];    // [NEDGES] int32 (sorted)
    const int*   edge_col = (const int*)d_in[2];    // [NEDGES] int32
    const float* edge_val = (const float*)d_in[3];  // [NEDGES] fp32
    const float* weight   = (const float*)d_in[4];  // [DIM, DIM] fp32
    const float* bias     = (const float*)d_in[5];  // [DIM] fp32
    float* out = (float*)d_out;                     // [NNODES, DIM] fp32

    char* ws = (char*)d_ws;
    // layout: y bf16 [NNODES*DIM] | row_ptr int[NNODES+1] | Wt bf16 [DIM*DIM]
    u16* y       = (u16*)ws;                               // 25,600,000 B
    int* row_ptr = (int*)(ws + (size_t)NNODES * DIM * 2);  // 400,004 B
    u16* wt      = (u16*)(ws + 26000128);                  // 32,768 B (16B aligned)

    prep_wt<<<(DIM * DIM + 255) / 256, 256, 0, stream>>>(weight, wt);
    build_row_ptr<<<(NNODES + 1 + 255) / 256, 256, 0, stream>>>(edge_row, row_ptr);

    // y = x @ W : 6250 wave-rows of 16, 4 waves/block -> 1563 blocks
    gemm_xw<<<(NNODES / 16 + 3) / 4, 256, 0, stream>>>(x, wt, y);

    // out = A @ y + bias : one wave per (row, colhalf), 2-phase column split
    spmm<<<2 * (NNODES / 4), 256, 0, stream>>>(row_ptr, edge_col, edge_val, y, bias, out);
}